// Round 7
// baseline (49.207 us; speedup 1.0000x reference)
//
#include <hip/hip_runtime.h>

// One-way Chamfer (L1, K=1): out[0] = mean_i min_j ||x_i - y_j||_1 ; out[1..N] = 0
// N = M = 16384, D = 3, fp32.
//
// R7: LDS broadcast was the structural bottleneck (every y costs ~12cyc of
// CU-shared LDS pipe per wave; R6 ran the pipe at 82% of the VALU timeline).
// New structure: y-points live in lane registers (64 y per wave, coalesced
// global loads), broadcast via v_readlane -> SGPR, consumed as src0 of
// v_sub_f32 (VOP2: 1 SGPR read/instr, y is the only SGPR operand). Zero LDS,
// zero barriers. 6 readlanes per 2 y over RB=8 x-points = 5.87 instr/pair
// -> 20us VALU floor. Subs operand-swapped (y-x; abs kills the sign).

#define TPB 256
#define RB 8
#define PTS_PER_BLOCK (TPB * RB)   // 2048
#define YSEG 128                   // y-points per block (2 phases of 64)

__device__ __forceinline__ float rl(float v, int l) {
    return __uint_as_float((unsigned)__builtin_amdgcn_readlane((int)__float_as_uint(v), l));
}

// MR = min3(MR, |a-y0|_1, |a-y1|_1); y components are SGPRs (src0), 11 instr.
#define DIST2S(MR, AXv, AYv, AZv, Y0X, Y0Y, Y0Z, Y1X, Y1Y, Y1Z)           \
  {                                                                        \
    float t0, t1, t2, t3, t4;                                              \
    asm("v_sub_f32 %1, %9, %6\n\t"                                         \
        "v_sub_f32 %2, %10, %7\n\t"                                        \
        "v_sub_f32 %3, %11, %8\n\t"                                        \
        "v_sub_f32 %4, %12, %6\n\t"                                        \
        "v_sub_f32 %5, %13, %7\n\t"                                        \
        "v_add_f32 %1, |%1|, |%2|\n\t"                                     \
        "v_sub_f32 %2, %14, %8\n\t"                                        \
        "v_add_f32 %4, |%4|, |%5|\n\t"                                     \
        "v_add_f32 %1, %1, |%3|\n\t"                                       \
        "v_add_f32 %4, %4, |%2|\n\t"                                       \
        "v_min3_f32 %0, %0, %1, %4"                                        \
        : "+v"(MR), "=&v"(t0), "=&v"(t1), "=&v"(t2), "=&v"(t3), "=&v"(t4)  \
        : "v"(AXv), "v"(AYv), "v"(AZv),                                    \
          "s"(Y0X), "s"(Y0Y), "s"(Y0Z), "s"(Y1X), "s"(Y1Y), "s"(Y1Z));    \
  }

__global__ __launch_bounds__(TPB) void init_kernel(unsigned* __restrict__ minbits, int N) {
    // 0x7F7F7F7F = 3.39e38f: uint order == float order for nonneg floats
    const int i = blockIdx.x * TPB + threadIdx.x;
    uint4* p = (uint4*)minbits;
    if (i < N / 4) p[i] = make_uint4(0x7F7F7F7Fu, 0x7F7F7F7Fu, 0x7F7F7F7Fu, 0x7F7F7F7Fu);
    for (int k = (N / 4) * 4 + i; k < N; k += 1) { if (i == 0) minbits[k] = 0x7F7F7F7Fu; }
}

__global__ __launch_bounds__(TPB) void chamfer_kernel(
    const float* __restrict__ pc1, const float* __restrict__ flow,
    const float* __restrict__ pc2, unsigned* __restrict__ minbits,
    int N, int M) {
    const int t    = threadIdx.x;
    const int lane = t & 63;

    // load + deform this thread's 8 x-points (stride TPB for coalescing)
    const int ibase = blockIdx.x * PTS_PER_BLOCK + t;
    float ax[RB], ay[RB], az[RB];
#pragma unroll
    for (int r = 0; r < RB; ++r) {
        const int i = ibase + r * TPB;
        const int ic = (i < N) ? i : (N - 1);
        ax[r] = pc1[3 * ic]     + flow[3 * ic];
        ay[r] = pc1[3 * ic + 1] + flow[3 * ic + 1];
        az[r] = pc1[3 * ic + 2] + flow[3 * ic + 2];
    }

    float m[RB];
#pragma unroll
    for (int r = 0; r < RB; ++r) m[r] = 3.0e38f;

    const int ybase = blockIdx.y * YSEG;
    const int yend  = (ybase + YSEG < M) ? (ybase + YSEG) : M;
    const int nph   = (yend - ybase + 63) >> 6;

    // phase 0 loads: each lane holds one y-point (duplicate-clamped at tail:
    // duplicates of an existing y never change the min)
    int g = ybase + lane; if (g >= M) g = M - 1;
    float cyx = pc2[3 * g], cyy = pc2[3 * g + 1], cyz = pc2[3 * g + 2];

    for (int p = 0; p < nph; ++p) {
        float nyx, nyy, nyz;
        const bool more = (p + 1 < nph);
        if (more) {
            int h = ybase + (p + 1) * 64 + lane; if (h >= M) h = M - 1;
            nyx = pc2[3 * h]; nyy = pc2[3 * h + 1]; nyz = pc2[3 * h + 2];
        }
#pragma unroll
        for (int j = 0; j < 64; j += 2) {
            const float y0x = rl(cyx, j),     y0y = rl(cyy, j),     y0z = rl(cyz, j);
            const float y1x = rl(cyx, j + 1), y1y = rl(cyy, j + 1), y1z = rl(cyz, j + 1);
#pragma unroll
            for (int r = 0; r < RB; ++r) {
                DIST2S(m[r], ax[r], ay[r], az[r], y0x, y0y, y0z, y1x, y1y, y1z);
            }
        }
        if (more) { cyx = nyx; cyy = nyy; cyz = nyz; }
    }

    // exact, order-independent combine: uint order == float order for nonneg
#pragma unroll
    for (int r = 0; r < RB; ++r) {
        const int i = ibase + r * TPB;
        if (i < N) atomicMin(&minbits[i], __float_as_uint(m[r]));
    }
}

// single block: writes the zeros output AND out[0] = sum(min)/N
__global__ __launch_bounds__(1024) void reduce_kernel(
    const unsigned* __restrict__ minbits, float* __restrict__ out,
    int N, int out_size) {
    // zero d_out (element 0 belongs to thread 0, which later overwrites it)
    float4* o4 = (float4*)out;
    const int n4 = out_size / 4;
    for (int k = threadIdx.x; k < n4; k += 1024)
        o4[k] = make_float4(0.f, 0.f, 0.f, 0.f);
    for (int k = n4 * 4 + threadIdx.x; k < out_size; k += 1024)
        out[k] = 0.f;

    float s = 0.0f;
    const uint4* p = (const uint4*)minbits;
    for (int k = threadIdx.x; k < N / 4; k += 1024) {
        uint4 v = p[k];
        s += __uint_as_float(v.x) + __uint_as_float(v.y) +
             __uint_as_float(v.z) + __uint_as_float(v.w);
    }
    for (int k = (N / 4) * 4 + threadIdx.x; k < N; k += 1024)
        s += __uint_as_float(minbits[k]);
#pragma unroll
    for (int off = 32; off > 0; off >>= 1) s += __shfl_down(s, off, 64);
    __shared__ float ls[16];
    const int wid = threadIdx.x >> 6, lane = threadIdx.x & 63;
    if (lane == 0) ls[wid] = s;
    __syncthreads();
    if (threadIdx.x == 0) {
        float tot = 0.0f;
        for (int w = 0; w < 16; ++w) tot += ls[w];
        out[0] = tot / (float)N;
    }
}

extern "C" void kernel_launch(void* const* d_in, const int* in_sizes, int n_in,
                              void* d_out, int out_size, void* d_ws, size_t ws_size,
                              hipStream_t stream) {
    const float* pc1  = (const float*)d_in[0];
    const float* flow = (const float*)d_in[1];
    const float* pc2  = (const float*)d_in[2];
    float* out = (float*)d_out;

    const int N = in_sizes[0] / 3;
    const int M = in_sizes[2] / 3;

    unsigned* minbits = (unsigned*)d_ws;

    const int nbN    = (N + PTS_PER_BLOCK - 1) / PTS_PER_BLOCK;  // 8
    const int msplit = (M + YSEG - 1) / YSEG;                    // 128 -> grid 1024

    init_kernel<<<(N / 4 + TPB - 1) / TPB, TPB, 0, stream>>>(minbits, N);
    chamfer_kernel<<<dim3(nbN, msplit), TPB, 0, stream>>>(pc1, flow, pc2, minbits, N, M);
    reduce_kernel<<<1, 1024, 0, stream>>>(minbits, out, N, out_size);
}

// Round 8
// 48.183 us; speedup vs baseline: 1.0212x; 1.0212x over previous
//
#include <hip/hip_runtime.h>

// One-way Chamfer (L1, K=1): out[0] = mean_i min_j ||x_i - y_j||_1 ; out[1..N] = 0
// N = M = 16384, D = 3, fp32.
//
// R8: broadcast y via the SCALAR pipe. R7 proved readlane-broadcast costs
// VALU issue + SGPR-hazard stalls (10.7 instr/pair effective); R1-R6 proved
// LDS broadcast costs ~12cyc/16B/wave of CU-shared LDS pipe. s_load_dwordx16
// into SGPR tuples costs the VALU pipe NOTHING: inner loop is exactly the
// 11-instr DIST2S per 2 pairs (5.5/pair = 18.8us floor). 8-y groups (24
// dwords = x16+x8), ping-pong double buffer, waits via volatile asm with
// "+s" on the buffers so consumers can't hoist above the lgkmcnt (rule #18).
// No LDS, no barriers -> grid 2048 = 8 blocks/CU, all resident.

#define TPB 256
#define RB 8
#define PTS_PER_BLOCK (TPB * RB)   // 2048
#define YSEG 64                    // y-points per block = 8 groups of 8
#define NITER (YSEG / 16)          // unroll-2 loop iterations (4)

typedef float sf16 __attribute__((ext_vector_type(16)));
typedef float sf8  __attribute__((ext_vector_type(8)));

// issue the 24-dword (8 y-point) group load; byte offsets are string literals
#define SLOAD24(B16, B8, PTR, O16, O8)                                     \
  asm volatile("s_load_dwordx16 %0, %2, " O16 "\n\t"                       \
               "s_load_dwordx8  %1, %2, " O8                               \
               : "=s"(B16), "=s"(B8) : "s"(PTR));

// wait for ALL outstanding SMEM; "+s" makes every consumer of the buffers
// data-dependent on this asm so the compiler cannot hoist reads above it
#define SWAIT(B16, B8)                                                     \
  asm volatile("s_waitcnt lgkmcnt(0)" : "+s"(B16), "+s"(B8));

// MR = min3(MR, |a-y0|_1, |a-y1|_1); y components are SGPRs (src0 of VOP2),
// 11 VALU instrs / 2 pairs, chains interleaved, abs as src modifiers.
#define DIST2S(MR, AXv, AYv, AZv, Y0X, Y0Y, Y0Z, Y1X, Y1Y, Y1Z)           \
  {                                                                        \
    float t0, t1, t2, t3, t4;                                              \
    asm("v_sub_f32 %1, %9, %6\n\t"                                         \
        "v_sub_f32 %2, %10, %7\n\t"                                        \
        "v_sub_f32 %3, %11, %8\n\t"                                        \
        "v_sub_f32 %4, %12, %6\n\t"                                        \
        "v_sub_f32 %5, %13, %7\n\t"                                        \
        "v_add_f32 %1, |%1|, |%2|\n\t"                                     \
        "v_sub_f32 %2, %14, %8\n\t"                                        \
        "v_add_f32 %4, |%4|, |%5|\n\t"                                     \
        "v_add_f32 %1, %1, |%3|\n\t"                                       \
        "v_add_f32 %4, %4, |%2|\n\t"                                       \
        "v_min3_f32 %0, %0, %1, %4"                                        \
        : "+v"(MR), "=&v"(t0), "=&v"(t1), "=&v"(t2), "=&v"(t3), "=&v"(t4)  \
        : "v"(AXv), "v"(AYv), "v"(AZv),                                    \
          "s"(Y0X), "s"(Y0Y), "s"(Y0Z), "s"(Y1X), "s"(Y1Y), "s"(Y1Z));    \
  }

// 8 y-points (one group) x RB x-points; pair-major so each m[r] chain has
// 44 instrs between dependent min3 writes
#define COMPUTE8(G16, G8)                                                  \
  {                                                                        \
    _Pragma("unroll")                                                      \
    for (int r = 0; r < RB; ++r)                                           \
      DIST2S(m[r], ax[r], ay[r], az[r],                                    \
             G16[0], G16[1], G16[2], G16[3], G16[4], G16[5]);              \
    _Pragma("unroll")                                                      \
    for (int r = 0; r < RB; ++r)                                           \
      DIST2S(m[r], ax[r], ay[r], az[r],                                    \
             G16[6], G16[7], G16[8], G16[9], G16[10], G16[11]);            \
    _Pragma("unroll")                                                      \
    for (int r = 0; r < RB; ++r)                                           \
      DIST2S(m[r], ax[r], ay[r], az[r],                                    \
             G16[12], G16[13], G16[14], G16[15], G8[0], G8[1]);            \
    _Pragma("unroll")                                                      \
    for (int r = 0; r < RB; ++r)                                           \
      DIST2S(m[r], ax[r], ay[r], az[r],                                    \
             G8[2], G8[3], G8[4], G8[5], G8[6], G8[7]);                    \
  }

__global__ __launch_bounds__(TPB) void init_kernel(unsigned* __restrict__ minbits, int N4) {
    // 0x7F7F7F7F = 3.39e38f: uint order == float order for nonneg floats
    const int i = blockIdx.x * TPB + threadIdx.x;
    uint4* p = (uint4*)minbits;
    if (i < N4) p[i] = make_uint4(0x7F7F7F7Fu, 0x7F7F7F7Fu, 0x7F7F7F7Fu, 0x7F7F7F7Fu);
}

__global__ __launch_bounds__(TPB, 8) void chamfer_kernel(
    const float* __restrict__ pc1, const float* __restrict__ flow,
    const float* __restrict__ pc2, unsigned* __restrict__ minbits,
    int N, int M) {
    const int t = threadIdx.x;

    // load + deform this thread's 8 x-points (stride TPB for coalescing)
    const int ibase = blockIdx.x * PTS_PER_BLOCK + t;
    float ax[RB], ay[RB], az[RB];
#pragma unroll
    for (int r = 0; r < RB; ++r) {
        const int i = ibase + r * TPB;
        const int ic = (i < N) ? i : (N - 1);
        ax[r] = pc1[3 * ic]     + flow[3 * ic];
        ay[r] = pc1[3 * ic + 1] + flow[3 * ic + 1];
        az[r] = pc1[3 * ic + 2] + flow[3 * ic + 2];
    }

    float m[RB];
#pragma unroll
    for (int r = 0; r < RB; ++r) m[r] = 3.0e38f;

    const int ybase = blockIdx.y * YSEG;
    const int yend  = (ybase + YSEG < M) ? (ybase + YSEG) : M;

    if (yend - ybase == YSEG) {
        const float* yp = pc2 + (size_t)3 * (size_t)ybase;
        sf16 A16, B16; sf8 A8, B8;
        SLOAD24(A16, A8, yp, "0", "64");           // group 0
#pragma unroll 1
        for (int it = 0; it < NITER; ++it) {
            SWAIT(A16, A8);                        // group 2it ready
            SLOAD24(B16, B8, yp, "96", "160");     // prefetch group 2it+1
            COMPUTE8(A16, A8);                     // 352 VALU instrs
            SWAIT(B16, B8);
            if (it + 1 < NITER)
                SLOAD24(A16, A8, yp, "192", "256");// prefetch group 2it+2
            COMPUTE8(B16, B8);
            yp += 48;
        }
    } else {
        // generic tail path (not hit for M % YSEG == 0)
        for (int j = ybase; j < yend; ++j) {
            const float yx = pc2[3 * j], yy = pc2[3 * j + 1], yz = pc2[3 * j + 2];
#pragma unroll
            for (int r = 0; r < RB; ++r)
                m[r] = fminf(m[r], fabsf(ax[r] - yx) + fabsf(ay[r] - yy) + fabsf(az[r] - yz));
        }
    }

    // exact, order-independent combine: uint order == float order for nonneg
#pragma unroll
    for (int r = 0; r < RB; ++r) {
        const int i = ibase + r * TPB;
        if (i < N) atomicMin(&minbits[i], __float_as_uint(m[r]));
    }
}

// single block: writes the zeros output AND out[0] = sum(min)/N
__global__ __launch_bounds__(1024) void reduce_kernel(
    const unsigned* __restrict__ minbits, float* __restrict__ out,
    int N, int out_size) {
    float4* o4 = (float4*)out;
    const int n4 = out_size / 4;
    for (int k = threadIdx.x; k < n4; k += 1024)
        o4[k] = make_float4(0.f, 0.f, 0.f, 0.f);
    for (int k = n4 * 4 + threadIdx.x; k < out_size; k += 1024)
        out[k] = 0.f;

    float s = 0.0f;
    const uint4* p = (const uint4*)minbits;
    for (int k = threadIdx.x; k < N / 4; k += 1024) {
        uint4 v = p[k];
        s += __uint_as_float(v.x) + __uint_as_float(v.y) +
             __uint_as_float(v.z) + __uint_as_float(v.w);
    }
    for (int k = (N / 4) * 4 + threadIdx.x; k < N; k += 1024)
        s += __uint_as_float(minbits[k]);
#pragma unroll
    for (int off = 32; off > 0; off >>= 1) s += __shfl_down(s, off, 64);
    __shared__ float ls[16];
    const int wid = threadIdx.x >> 6, lane = threadIdx.x & 63;
    if (lane == 0) ls[wid] = s;
    __syncthreads();
    if (threadIdx.x == 0) {
        float tot = 0.0f;
        for (int w = 0; w < 16; ++w) tot += ls[w];
        out[0] = tot / (float)N;
    }
}

extern "C" void kernel_launch(void* const* d_in, const int* in_sizes, int n_in,
                              void* d_out, int out_size, void* d_ws, size_t ws_size,
                              hipStream_t stream) {
    const float* pc1  = (const float*)d_in[0];
    const float* flow = (const float*)d_in[1];
    const float* pc2  = (const float*)d_in[2];
    float* out = (float*)d_out;

    const int N = in_sizes[0] / 3;
    const int M = in_sizes[2] / 3;

    unsigned* minbits = (unsigned*)d_ws;

    const int nbN    = (N + PTS_PER_BLOCK - 1) / PTS_PER_BLOCK;  // 8
    const int msplit = (M + YSEG - 1) / YSEG;                    // 256 -> grid 2048

    init_kernel<<<(N / 4 + TPB - 1) / TPB, TPB, 0, stream>>>(minbits, N / 4);
    chamfer_kernel<<<dim3(nbN, msplit), TPB, 0, stream>>>(pc1, flow, pc2, minbits, N, M);
    reduce_kernel<<<1, 1024, 0, stream>>>(minbits, out, N, out_size);
}

// Round 9
// 44.763 us; speedup vs baseline: 1.0993x; 1.0764x over previous
//
#include <hip/hip_runtime.h>

// One-way Chamfer (L1, K=1): out[0] = mean_i min_j ||x_i - y_j||_1 ; out[1..N] = 0
// N = M = 16384, D = 3, fp32.
//
// R9: R8's counters unmasked the atomic combine as the hidden cost
// (WRITE_SIZE 48MB for a 64KB buffer; occupancy 48% on a statically-full
// grid = compute phase + long memory-side atomic drain). Keep R8's scalar-
// pipe broadcast inner loop (exactly 5.5 VALU instr/pair, y via
// s_load_dwordx16/x8 double-buffer) but: (1) partial mins are STORED
// coalesced to partial[yseg][x] (8MB streaming) and combined by a reduce
// kernel with 8 loads in flight - zero atomics, zero init; (2) RB=4,
// msplit=128 halves the x-reload redundancy (24-load prologue).

#define TPB 256
#define RB 4
#define PTS_PER_BLOCK (TPB * RB)   // 1024
#define YSEG 128                   // y-points per block = 16 groups of 8
#define NITER (YSEG / 16)          // unroll-2 loop iterations (8)

typedef float sf16 __attribute__((ext_vector_type(16)));
typedef float sf8  __attribute__((ext_vector_type(8)));

// issue the 24-dword (8 y-point) group load; byte offsets are string literals
#define SLOAD24(B16, B8, PTR, O16, O8)                                     \
  asm volatile("s_load_dwordx16 %0, %2, " O16 "\n\t"                       \
               "s_load_dwordx8  %1, %2, " O8                               \
               : "=s"(B16), "=s"(B8) : "s"(PTR));

// wait for ALL outstanding SMEM; "+s" makes consumers of the buffers
// data-dependent on this asm so reads can't be hoisted above the wait
#define SWAIT(B16, B8)                                                     \
  asm volatile("s_waitcnt lgkmcnt(0)" : "+s"(B16), "+s"(B8));

// MR = min3(MR, |a-y0|_1, |a-y1|_1); y components are SGPRs (src0 of VOP2),
// 11 VALU instrs / 2 pairs, chains interleaved, abs as src modifiers.
#define DIST2S(MR, AXv, AYv, AZv, Y0X, Y0Y, Y0Z, Y1X, Y1Y, Y1Z)           \
  {                                                                        \
    float t0, t1, t2, t3, t4;                                              \
    asm("v_sub_f32 %1, %9, %6\n\t"                                         \
        "v_sub_f32 %2, %10, %7\n\t"                                        \
        "v_sub_f32 %3, %11, %8\n\t"                                        \
        "v_sub_f32 %4, %12, %6\n\t"                                        \
        "v_sub_f32 %5, %13, %7\n\t"                                        \
        "v_add_f32 %1, |%1|, |%2|\n\t"                                     \
        "v_sub_f32 %2, %14, %8\n\t"                                        \
        "v_add_f32 %4, |%4|, |%5|\n\t"                                     \
        "v_add_f32 %1, %1, |%3|\n\t"                                       \
        "v_add_f32 %4, %4, |%2|\n\t"                                       \
        "v_min3_f32 %0, %0, %1, %4"                                        \
        : "+v"(MR), "=&v"(t0), "=&v"(t1), "=&v"(t2), "=&v"(t3), "=&v"(t4)  \
        : "v"(AXv), "v"(AYv), "v"(AZv),                                    \
          "s"(Y0X), "s"(Y0Y), "s"(Y0Z), "s"(Y1X), "s"(Y1Y), "s"(Y1Z));    \
  }

// 8 y-points (one group) x RB x-points; pair-major: each m[r] dep chain is
// RB DIST2S (44 instrs) apart
#define COMPUTE8(G16, G8)                                                  \
  {                                                                        \
    _Pragma("unroll")                                                      \
    for (int r = 0; r < RB; ++r)                                           \
      DIST2S(m[r], ax[r], ay[r], az[r],                                    \
             G16[0], G16[1], G16[2], G16[3], G16[4], G16[5]);              \
    _Pragma("unroll")                                                      \
    for (int r = 0; r < RB; ++r)                                           \
      DIST2S(m[r], ax[r], ay[r], az[r],                                    \
             G16[6], G16[7], G16[8], G16[9], G16[10], G16[11]);            \
    _Pragma("unroll")                                                      \
    for (int r = 0; r < RB; ++r)                                           \
      DIST2S(m[r], ax[r], ay[r], az[r],                                    \
             G16[12], G16[13], G16[14], G16[15], G8[0], G8[1]);            \
    _Pragma("unroll")                                                      \
    for (int r = 0; r < RB; ++r)                                           \
      DIST2S(m[r], ax[r], ay[r], az[r],                                    \
             G8[2], G8[3], G8[4], G8[5], G8[6], G8[7]);                    \
  }

__global__ __launch_bounds__(TPB, 8) void chamfer_kernel(
    const float* __restrict__ pc1, const float* __restrict__ flow,
    const float* __restrict__ pc2, float* __restrict__ partial,
    int N, int M) {
    const int t = threadIdx.x;

    // load + deform this thread's 4 x-points (stride TPB for coalescing)
    const int ibase = blockIdx.x * PTS_PER_BLOCK + t;
    float ax[RB], ay[RB], az[RB];
#pragma unroll
    for (int r = 0; r < RB; ++r) {
        const int i = ibase + r * TPB;
        const int ic = (i < N) ? i : (N - 1);
        ax[r] = pc1[3 * ic]     + flow[3 * ic];
        ay[r] = pc1[3 * ic + 1] + flow[3 * ic + 1];
        az[r] = pc1[3 * ic + 2] + flow[3 * ic + 2];
    }

    float m[RB];
#pragma unroll
    for (int r = 0; r < RB; ++r) m[r] = 3.0e38f;

    const int ybase = blockIdx.y * YSEG;
    const int yend  = (ybase + YSEG < M) ? (ybase + YSEG) : M;

    if (yend - ybase == YSEG) {
        const float* yp = pc2 + (size_t)3 * (size_t)ybase;
        sf16 A16, B16; sf8 A8, B8;
        SLOAD24(A16, A8, yp, "0", "64");           // group 0
#pragma unroll 1
        for (int it = 0; it < NITER; ++it) {
            SWAIT(A16, A8);                        // group 2it ready
            SLOAD24(B16, B8, yp, "96", "160");     // prefetch group 2it+1
            COMPUTE8(A16, A8);                     // 176 VALU instrs
            SWAIT(B16, B8);
            if (it + 1 < NITER)
                SLOAD24(A16, A8, yp, "192", "256");// prefetch group 2it+2
            COMPUTE8(B16, B8);
            yp += 48;
        }
    } else {
        // generic tail path (not hit for M % YSEG == 0)
        for (int j = ybase; j < yend; ++j) {
            const float yx = pc2[3 * j], yy = pc2[3 * j + 1], yz = pc2[3 * j + 2];
#pragma unroll
            for (int r = 0; r < RB; ++r)
                m[r] = fminf(m[r], fabsf(ax[r] - yx) + fabsf(ay[r] - yy) + fabsf(az[r] - yz));
        }
    }

    // coalesced partial-min stores; combined by reduce_kernel (no atomics)
    float* __restrict__ prow = partial + (size_t)blockIdx.y * (size_t)N;
#pragma unroll
    for (int r = 0; r < RB; ++r) {
        const int i = ibase + r * TPB;
        if (i < N) prow[i] = m[r];
    }
}

// column-min over S rows + per-block sums; also zeroes out[1..N]
__global__ __launch_bounds__(256) void reduce_kernel(
    const float* __restrict__ partial, float* __restrict__ blocksums,
    float* __restrict__ out, int N, int S, int out_size) {
    const int i = blockIdx.x * 256 + threadIdx.x;
    if (1 + i < out_size) out[1 + i] = 0.0f;   // freespace_loss zeros

    float v = 0.0f;
    if (i < N) {
        float m0 = 3.0e38f, m1 = 3.0e38f, m2 = 3.0e38f, m3 = 3.0e38f;
        float m4 = 3.0e38f, m5 = 3.0e38f, m6 = 3.0e38f, m7 = 3.0e38f;
        const float* p = partial + i;
        int s = 0;
        for (; s + 8 <= S; s += 8) {      // 8 independent loads in flight
            m0 = fminf(m0, p[(size_t)(s + 0) * N]);
            m1 = fminf(m1, p[(size_t)(s + 1) * N]);
            m2 = fminf(m2, p[(size_t)(s + 2) * N]);
            m3 = fminf(m3, p[(size_t)(s + 3) * N]);
            m4 = fminf(m4, p[(size_t)(s + 4) * N]);
            m5 = fminf(m5, p[(size_t)(s + 5) * N]);
            m6 = fminf(m6, p[(size_t)(s + 6) * N]);
            m7 = fminf(m7, p[(size_t)(s + 7) * N]);
        }
        for (; s < S; ++s) m0 = fminf(m0, p[(size_t)s * N]);
        v = fminf(fminf(fminf(m0, m1), fminf(m2, m3)),
                  fminf(fminf(m4, m5), fminf(m6, m7)));
    }

    float sv = (i < N) ? v : 0.0f;
#pragma unroll
    for (int off = 32; off > 0; off >>= 1) sv += __shfl_down(sv, off, 64);
    __shared__ float ls[4];
    const int wid = threadIdx.x >> 6, lane = threadIdx.x & 63;
    if (lane == 0) ls[wid] = sv;
    __syncthreads();
    if (threadIdx.x == 0)
        blocksums[blockIdx.x] = ls[0] + ls[1] + ls[2] + ls[3];
}

__global__ void final_kernel(const float* __restrict__ blocksums, int nPart,
                             float* __restrict__ out, float invN) {
    float v = 0.0f;
    for (int k = threadIdx.x; k < nPart; k += 64) v += blocksums[k];
#pragma unroll
    for (int off = 32; off > 0; off >>= 1) v += __shfl_down(v, off, 64);
    if (threadIdx.x == 0) out[0] = v * invN;
}

extern "C" void kernel_launch(void* const* d_in, const int* in_sizes, int n_in,
                              void* d_out, int out_size, void* d_ws, size_t ws_size,
                              hipStream_t stream) {
    const float* pc1  = (const float*)d_in[0];
    const float* flow = (const float*)d_in[1];
    const float* pc2  = (const float*)d_in[2];
    float* out = (float*)d_out;

    const int N = in_sizes[0] / 3;
    const int M = in_sizes[2] / 3;

    const int nbN    = (N + PTS_PER_BLOCK - 1) / PTS_PER_BLOCK;  // 16
    const int msplit = (M + YSEG - 1) / YSEG;                    // 128 -> grid 2048
    const int nb2    = (N + 255) / 256;                          // 64

    float* partial   = (float*)d_ws;                              // msplit*N floats (8 MB)
    float* blocksums = (float*)((char*)d_ws +
                        (size_t)msplit * (size_t)N * sizeof(float));

    chamfer_kernel<<<dim3(nbN, msplit), TPB, 0, stream>>>(pc1, flow, pc2, partial, N, M);
    reduce_kernel<<<nb2, 256, 0, stream>>>(partial, blocksums, out, N, msplit, out_size);
    final_kernel<<<1, 64, 0, stream>>>(blocksums, nb2, out, 1.0f / (float)N);
}

// Round 10
// 40.342 us; speedup vs baseline: 1.2198x; 1.1096x over previous
//
#include <hip/hip_runtime.h>

// One-way Chamfer (L1, K=1): out[0] = mean_i min_j ||x_i - y_j||_1 ; out[1..N] = 0
// N = M = 16384, D = 3, fp32.
//
// R10: R9 proved atomics were NOT the drain (removing them: -3.4us). Revised
// model: per-SIMD VALU issue is already ~the floor (R8 VALUBusy 85% is a
// per-CU union over 4 SIMDs ~= 45%/SIMD ~= 19us issue); realistic floor is
// ~27us after the m07 calibration (full-chip fp32 VALU sustains 103/157 of
// nominal). Cut what remains: x-side redundancy (prologue reload of pc1/flow
// msplit times) halves via RB=2/YSEG=256 (grid 32x64=2048, still 8 blocks/CU
// full occupancy); partial buffer 8->4MB; reduce gets 128 blocks.

#define TPB 256
#define RB 2
#define PTS_PER_BLOCK (TPB * RB)   // 512
#define YSEG 256                   // y-points per block = 32 groups of 8
#define NITER (YSEG / 16)          // unroll-2 loop iterations (16)

typedef float sf16 __attribute__((ext_vector_type(16)));
typedef float sf8  __attribute__((ext_vector_type(8)));

// issue the 24-dword (8 y-point) group load; byte offsets are string literals
#define SLOAD24(B16, B8, PTR, O16, O8)                                     \
  asm volatile("s_load_dwordx16 %0, %2, " O16 "\n\t"                       \
               "s_load_dwordx8  %1, %2, " O8                               \
               : "=s"(B16), "=s"(B8) : "s"(PTR));

// wait for ALL outstanding SMEM; "+s" makes consumers of the buffers
// data-dependent on this asm so reads can't be hoisted above the wait
#define SWAIT(B16, B8)                                                     \
  asm volatile("s_waitcnt lgkmcnt(0)" : "+s"(B16), "+s"(B8));

// MR = min3(MR, |a-y0|_1, |a-y1|_1); y components are SGPRs (src0 of VOP2),
// 11 VALU instrs / 2 pairs, chains interleaved, abs as src modifiers.
#define DIST2S(MR, AXv, AYv, AZv, Y0X, Y0Y, Y0Z, Y1X, Y1Y, Y1Z)           \
  {                                                                        \
    float t0, t1, t2, t3, t4;                                              \
    asm("v_sub_f32 %1, %9, %6\n\t"                                         \
        "v_sub_f32 %2, %10, %7\n\t"                                        \
        "v_sub_f32 %3, %11, %8\n\t"                                        \
        "v_sub_f32 %4, %12, %6\n\t"                                        \
        "v_sub_f32 %5, %13, %7\n\t"                                        \
        "v_add_f32 %1, |%1|, |%2|\n\t"                                     \
        "v_sub_f32 %2, %14, %8\n\t"                                        \
        "v_add_f32 %4, |%4|, |%5|\n\t"                                     \
        "v_add_f32 %1, %1, |%3|\n\t"                                       \
        "v_add_f32 %4, %4, |%2|\n\t"                                       \
        "v_min3_f32 %0, %0, %1, %4"                                        \
        : "+v"(MR), "=&v"(t0), "=&v"(t1), "=&v"(t2), "=&v"(t3), "=&v"(t4)  \
        : "v"(AXv), "v"(AYv), "v"(AZv),                                    \
          "s"(Y0X), "s"(Y0Y), "s"(Y0Z), "s"(Y1X), "s"(Y1Y), "s"(Y1Z));    \
  }

// 8 y-points (one group) x RB x-points
#define COMPUTE8(G16, G8)                                                  \
  {                                                                        \
    _Pragma("unroll")                                                      \
    for (int r = 0; r < RB; ++r)                                           \
      DIST2S(m[r], ax[r], ay[r], az[r],                                    \
             G16[0], G16[1], G16[2], G16[3], G16[4], G16[5]);              \
    _Pragma("unroll")                                                      \
    for (int r = 0; r < RB; ++r)                                           \
      DIST2S(m[r], ax[r], ay[r], az[r],                                    \
             G16[6], G16[7], G16[8], G16[9], G16[10], G16[11]);            \
    _Pragma("unroll")                                                      \
    for (int r = 0; r < RB; ++r)                                           \
      DIST2S(m[r], ax[r], ay[r], az[r],                                    \
             G16[12], G16[13], G16[14], G16[15], G8[0], G8[1]);            \
    _Pragma("unroll")                                                      \
    for (int r = 0; r < RB; ++r)                                           \
      DIST2S(m[r], ax[r], ay[r], az[r],                                    \
             G8[2], G8[3], G8[4], G8[5], G8[6], G8[7]);                    \
  }

__global__ __launch_bounds__(TPB, 8) void chamfer_kernel(
    const float* __restrict__ pc1, const float* __restrict__ flow,
    const float* __restrict__ pc2, float* __restrict__ partial,
    int N, int M) {
    const int t = threadIdx.x;

    // load + deform this thread's 2 x-points (stride TPB for coalescing)
    const int ibase = blockIdx.x * PTS_PER_BLOCK + t;
    float ax[RB], ay[RB], az[RB];
#pragma unroll
    for (int r = 0; r < RB; ++r) {
        const int i = ibase + r * TPB;
        const int ic = (i < N) ? i : (N - 1);
        ax[r] = pc1[3 * ic]     + flow[3 * ic];
        ay[r] = pc1[3 * ic + 1] + flow[3 * ic + 1];
        az[r] = pc1[3 * ic + 2] + flow[3 * ic + 2];
    }

    float m[RB];
#pragma unroll
    for (int r = 0; r < RB; ++r) m[r] = 3.0e38f;

    const int ybase = blockIdx.y * YSEG;
    const int yend  = (ybase + YSEG < M) ? (ybase + YSEG) : M;

    if (yend - ybase == YSEG) {
        const float* yp = pc2 + (size_t)3 * (size_t)ybase;
        sf16 A16, B16; sf8 A8, B8;
        SLOAD24(A16, A8, yp, "0", "64");           // group 0
#pragma unroll 1
        for (int it = 0; it < NITER; ++it) {
            SWAIT(A16, A8);                        // group 2it ready
            SLOAD24(B16, B8, yp, "96", "160");     // prefetch group 2it+1
            COMPUTE8(A16, A8);                     // 88 VALU instrs
            SWAIT(B16, B8);
            if (it + 1 < NITER)
                SLOAD24(A16, A8, yp, "192", "256");// prefetch group 2it+2
            COMPUTE8(B16, B8);
            yp += 48;
        }
    } else {
        // generic tail path (not hit for M % YSEG == 0)
        for (int j = ybase; j < yend; ++j) {
            const float yx = pc2[3 * j], yy = pc2[3 * j + 1], yz = pc2[3 * j + 2];
#pragma unroll
            for (int r = 0; r < RB; ++r)
                m[r] = fminf(m[r], fabsf(ax[r] - yx) + fabsf(ay[r] - yy) + fabsf(az[r] - yz));
        }
    }

    // coalesced partial-min stores; combined by reduce_kernel (no atomics)
    float* __restrict__ prow = partial + (size_t)blockIdx.y * (size_t)N;
#pragma unroll
    for (int r = 0; r < RB; ++r) {
        const int i = ibase + r * TPB;
        if (i < N) prow[i] = m[r];
    }
}

// column-min over S rows + per-block sums; also zeroes out[1..N]
#define RTPB 128
__global__ __launch_bounds__(RTPB) void reduce_kernel(
    const float* __restrict__ partial, float* __restrict__ blocksums,
    float* __restrict__ out, int N, int S, int out_size) {
    const int i = blockIdx.x * RTPB + threadIdx.x;
    if (1 + i < out_size) out[1 + i] = 0.0f;   // freespace_loss zeros

    float v = 0.0f;
    if (i < N) {
        float m0 = 3.0e38f, m1 = 3.0e38f, m2 = 3.0e38f, m3 = 3.0e38f;
        float m4 = 3.0e38f, m5 = 3.0e38f, m6 = 3.0e38f, m7 = 3.0e38f;
        const float* p = partial + i;
        int s = 0;
        for (; s + 8 <= S; s += 8) {      // 8 independent loads in flight
            m0 = fminf(m0, p[(size_t)(s + 0) * N]);
            m1 = fminf(m1, p[(size_t)(s + 1) * N]);
            m2 = fminf(m2, p[(size_t)(s + 2) * N]);
            m3 = fminf(m3, p[(size_t)(s + 3) * N]);
            m4 = fminf(m4, p[(size_t)(s + 4) * N]);
            m5 = fminf(m5, p[(size_t)(s + 5) * N]);
            m6 = fminf(m6, p[(size_t)(s + 6) * N]);
            m7 = fminf(m7, p[(size_t)(s + 7) * N]);
        }
        for (; s < S; ++s) m0 = fminf(m0, p[(size_t)s * N]);
        v = fminf(fminf(fminf(m0, m1), fminf(m2, m3)),
                  fminf(fminf(m4, m5), fminf(m6, m7)));
    }

    float sv = (i < N) ? v : 0.0f;
#pragma unroll
    for (int off = 32; off > 0; off >>= 1) sv += __shfl_down(sv, off, 64);
    __shared__ float ls[RTPB / 64];
    const int wid = threadIdx.x >> 6, lane = threadIdx.x & 63;
    if (lane == 0) ls[wid] = sv;
    __syncthreads();
    if (threadIdx.x == 0)
        blocksums[blockIdx.x] = ls[0] + ls[1];
}

__global__ void final_kernel(const float* __restrict__ blocksums, int nPart,
                             float* __restrict__ out, float invN) {
    float v = 0.0f;
    for (int k = threadIdx.x; k < nPart; k += 64) v += blocksums[k];
#pragma unroll
    for (int off = 32; off > 0; off >>= 1) v += __shfl_down(v, off, 64);
    if (threadIdx.x == 0) out[0] = v * invN;
}

extern "C" void kernel_launch(void* const* d_in, const int* in_sizes, int n_in,
                              void* d_out, int out_size, void* d_ws, size_t ws_size,
                              hipStream_t stream) {
    const float* pc1  = (const float*)d_in[0];
    const float* flow = (const float*)d_in[1];
    const float* pc2  = (const float*)d_in[2];
    float* out = (float*)d_out;

    const int N = in_sizes[0] / 3;
    const int M = in_sizes[2] / 3;

    const int nbN    = (N + PTS_PER_BLOCK - 1) / PTS_PER_BLOCK;  // 32
    const int msplit = (M + YSEG - 1) / YSEG;                    // 64 -> grid 2048
    const int nb2    = (N + RTPB - 1) / RTPB;                    // 128

    float* partial   = (float*)d_ws;                              // msplit*N floats (4 MB)
    float* blocksums = (float*)((char*)d_ws +
                        (size_t)msplit * (size_t)N * sizeof(float));

    chamfer_kernel<<<dim3(nbN, msplit), TPB, 0, stream>>>(pc1, flow, pc2, partial, N, M);
    reduce_kernel<<<nb2, RTPB, 0, stream>>>(partial, blocksums, out, N, msplit, out_size);
    final_kernel<<<1, 64, 0, stream>>>(blocksums, nb2, out, 1.0f / (float)N);
}